// Round 13
// baseline (81.811 us; speedup 1.0000x reference)
//
#include <hip/hip_runtime.h>
#include <cfloat>

typedef __bf16 bf16x8 __attribute__((ext_vector_type(8)));
typedef unsigned short ushort8 __attribute__((ext_vector_type(8)));
typedef float f32x16 __attribute__((ext_vector_type(16)));

#define S_SLICES 5   // 96 x 5 x 2 = 960 blocks = 3.75/CU, single batch at (256,4)

// fp32 -> bf16 bits, round-to-nearest-even
static __device__ __forceinline__ unsigned short f2bf(float x) {
    unsigned u = __float_as_uint(x);
    return (unsigned short)((u + 0x7FFFu + ((u >> 16) & 1u)) >> 16);
}
static __device__ __forceinline__ float bfbits2f(unsigned short h) {
    return __uint_as_float(((unsigned)h) << 16);
}

// Per point, build TWO 16-element K-vectors (verified round 7/8):
//  row vec: [-2hx,-2hy,-2hz, -2hx,-2hy,-2hz, -2lx,-2ly,-2lz, s1,s2,s3, 1,1,1, 0]
//  col vec: [ hx,  hy,  hz,   lx,  ly,  lz,   hx,  hy,  hz,  1,1,1, t1,t2,t3, 0]
//  => sum_k row[k]*col[k] = nrmRow + nrmCol - 2(hh+hl+lh) ~= d2 (err ~1e-4).
// Fragment storage: frag[tile*64 + q*32 + l5], point = tile*32+l5, k = q*8+j.
// Pad points get nrm=1e30 -> never win a min.
__global__ __launch_bounds__(256) void prep_kernel(
    const float* __restrict__ A, const float* __restrict__ B,
    ushort8* __restrict__ RFA, ushort8* __restrict__ CFA,
    ushort8* __restrict__ RFB, ushort8* __restrict__ CFB,
    float* __restrict__ hdr, int n, int m, int RTn, int RTm)
{
    const int i = blockIdx.x * 256 + threadIdx.x;
    if (i < 8) hdr[i] = 0.f;
    const unsigned short one = 0x3F80;

#pragma unroll
    for (int side = 0; side < 2; ++side) {
        const int cntPts = side ? RTm * 32 : RTn * 32;
        if (i >= cntPts) continue;
        const float* P = side ? B : A;
        const int lim = side ? m : n;
        ushort8* RF = side ? RFB : RFA;
        ushort8* CF = side ? CFB : CFA;

        float x = 0.f, y = 0.f, z = 0.f, nrm = 1e30f;
        if (i < lim) { x = P[3*i]; y = P[3*i+1]; z = P[3*i+2];
                       nrm = fmaf(x, x, fmaf(y, y, z * z)); }
        const unsigned short hx = f2bf(x), hy = f2bf(y), hz = f2bf(z);
        const unsigned short lx = f2bf(x - bfbits2f(hx)),
                             ly = f2bf(y - bfbits2f(hy)),
                             lz = f2bf(z - bfbits2f(hz));
        const unsigned short nhx = f2bf(-2.f * bfbits2f(hx)),
                             nhy = f2bf(-2.f * bfbits2f(hy)),
                             nhz = f2bf(-2.f * bfbits2f(hz));
        const unsigned short nlx = f2bf(-2.f * bfbits2f(lx)),
                             nly = f2bf(-2.f * bfbits2f(ly)),
                             nlz = f2bf(-2.f * bfbits2f(lz));
        float r = nrm;
        const unsigned short s1 = f2bf(r); r -= bfbits2f(s1);
        const unsigned short s2 = f2bf(r); r -= bfbits2f(s2);
        const unsigned short s3 = f2bf(r);

        const int t = i >> 5, l5 = i & 31;
        ushort8 rq0 = { nhx, nhy, nhz, nhx, nhy, nhz, nlx, nly };
        ushort8 rq1 = { nlz, s1, s2, s3, one, one, one, 0 };
        RF[t * 64 + l5]      = rq0;
        RF[t * 64 + 32 + l5] = rq1;
        ushort8 cq0 = { hx, hy, hz, lx, ly, lz, hx, hy };
        ushort8 cq1 = { hz, one, one, one, s1, s2, s3, 0 };
        CF[t * 64 + l5]      = cq0;
        CF[t * 64 + 32 + l5] = cq1;
    }
}

#define MFMA(b) __builtin_amdgcn_mfma_f32_32x32x16_bf16(afrag, (b), zc, 0, 0, 0)
#define MINC(C)                                             \
    _Pragma("unroll")                                       \
    for (int r = 0; r < 16; ++r) macc[r] = fminf(macc[r], (C)[r]);

// z=0: rows=A vs cols=B -> sbuf side 0 ("mins"); z=1: transposed ("mins_seeds").
// Round 8: (256,4) keeps C in VGPRs. Round 11/12: 4-deep prefetch helped
// (-5.8us), 2-row-tiles regressed; pairmin still ~115 cyc/tile exposed L2
// latency. Fix: 8-deep static queue -> load->use distance ~6 tile-segments
// (~300 issue cyc) > 200-cyc L2 latency, even single-wave.
__global__ __launch_bounds__(256, 4) void pairmin_kernel(
    const bf16x8* __restrict__ RFA, const bf16x8* __restrict__ CFA,
    const bf16x8* __restrict__ RFB, const bf16x8* __restrict__ CFB,
    float* __restrict__ sbuf, int RTn, int RTm)
{
    const int lane = threadIdx.x & 63;
    const int wave = threadIdx.x >> 6;

    const bf16x8* RF; const bf16x8* CF; float* sb; int rtCount, ctCount, stride;
    if (blockIdx.z == 0) { RF = RFA; CF = CFB; rtCount = RTn; ctCount = RTm;
                           sb = sbuf; stride = RTn * 32; }
    else                 { RF = RFB; CF = CFA; rtCount = RTm; ctCount = RTn;
                           sb = sbuf + (size_t)S_SLICES * RTn * 32;
                           stride = RTm * 32; }

    const int rt = blockIdx.x * 4 + wave;
    if (rt >= rtCount) return;                       // wave-uniform
    sb += (size_t)blockIdx.y * stride;

    const int ctPer = (ctCount + S_SLICES - 1) / S_SLICES;
    const int ctBeg = min(blockIdx.y * ctPer, ctCount);
    const int ctEnd = min(ctBeg + ctPer, ctCount);

    const bf16x8 afrag = RF[rt * 64 + lane];         // loop-invariant
    const f32x16 zc = {};

    float macc[16];
#pragma unroll
    for (int r = 0; r < 16; ++r) macc[r] = FLT_MAX;

    if (ctBeg < ctEnd) {
        int ct = ctBeg;
        const int last = ctEnd - 1;
        // 8-deep prefetch queue (prologue clamped; duplicates min-idempotent)
        bf16x8 q0 = CF[(size_t)ct * 64 + lane];
        bf16x8 q1 = CF[(size_t)min(ct + 1, last) * 64 + lane];
        bf16x8 q2 = CF[(size_t)min(ct + 2, last) * 64 + lane];
        bf16x8 q3 = CF[(size_t)min(ct + 3, last) * 64 + lane];
        bf16x8 q4 = CF[(size_t)min(ct + 4, last) * 64 + lane];
        bf16x8 q5 = CF[(size_t)min(ct + 5, last) * 64 + lane];
        bf16x8 q6 = CF[(size_t)min(ct + 6, last) * 64 + lane];
        bf16x8 q7 = CF[(size_t)min(ct + 7, last) * 64 + lane];
        f32x16 C0 = MFMA(q0);
        f32x16 C1 = MFMA(q1);

        // steady state, 8 tiles/iter. Invariant at top: C0=tile ct, C1=ct+1,
        // q2..q7 = ct+2..ct+7. Loads run 8 tiles ahead of their MFMA.
        for (; ct + 15 < ctEnd; ct += 8) {
            q0 = CF[(size_t)(ct +  8) * 64 + lane];  MINC(C0); C0 = MFMA(q2);
            q1 = CF[(size_t)(ct +  9) * 64 + lane];  MINC(C1); C1 = MFMA(q3);
            q2 = CF[(size_t)(ct + 10) * 64 + lane];  MINC(C0); C0 = MFMA(q4);
            q3 = CF[(size_t)(ct + 11) * 64 + lane];  MINC(C1); C1 = MFMA(q5);
            q4 = CF[(size_t)(ct + 12) * 64 + lane];  MINC(C0); C0 = MFMA(q6);
            q5 = CF[(size_t)(ct + 13) * 64 + lane];  MINC(C1); C1 = MFMA(q7);
            q6 = CF[(size_t)(ct + 14) * 64 + lane];  MINC(C0); C0 = MFMA(q0);
            q7 = CF[(size_t)(ct + 15) * 64 + lane];  MINC(C1); C1 = MFMA(q1);
        }
        // epilogue: C0/C1 hold ct/ct+1; q2..q7 hold clamped ct+2..ct+7
        MINC(C0); MINC(C1);
        if (ct + 2 < ctEnd) { const f32x16 C = MFMA(q2); MINC(C); }
        if (ct + 3 < ctEnd) { const f32x16 C = MFMA(q3); MINC(C); }
        if (ct + 4 < ctEnd) { const f32x16 C = MFMA(q4); MINC(C); }
        if (ct + 5 < ctEnd) { const f32x16 C = MFMA(q5); MINC(C); }
        if (ct + 6 < ctEnd) { const f32x16 C = MFMA(q6); MINC(C); }
        if (ct + 7 < ctEnd) { const f32x16 C = MFMA(q7); MINC(C); }
        for (int t = ct + 8; t < ctEnd; ++t) {
            const bf16x8 b = CF[(size_t)t * 64 + lane];
            const f32x16 C = MFMA(b);
            MINC(C);
        }
    }

    // reduce row mins across the 32 cols held in each 32-lane half
#pragma unroll
    for (int r = 0; r < 16; ++r) {
        float v = macc[r];
        v = fminf(v, __shfl_xor(v, 1, 64));
        v = fminf(v, __shfl_xor(v, 2, 64));
        v = fminf(v, __shfl_xor(v, 4, 64));
        v = fminf(v, __shfl_xor(v, 8, 64));
        v = fminf(v, __shfl_xor(v, 16, 64));
        macc[r] = v;
    }
    if ((lane & 31) == 0) {
        const int q4i = (lane >> 5) * 4;             // C map: row=(r&3)+8*(r>>2)+4*q
        float* dst = sb + rt * 32;
#pragma unroll
        for (int r = 0; r < 16; ++r)
            dst[(r & 3) + 8 * (r >> 2) + q4i] = macc[r];
    }
}

// out layout: [loss+loss_seeds, mins_seeds(m), loss, loss_seeds]
__global__ __launch_bounds__(256) void finalize_kernel(
    const float* __restrict__ sbuf, float* __restrict__ hdr,
    float* __restrict__ out, int n, int m, int RTn, int RTm)
{
    const int i = blockIdx.x * 256 + threadIdx.x;
    const int strideA = RTn * 32, strideB = RTm * 32;
    const float* sbB = sbuf + (size_t)S_SLICES * strideA;

    float sa = 0.f, sb_ = 0.f;
    if (i < n) {
        float s = FLT_MAX;
#pragma unroll
        for (int k = 0; k < S_SLICES; ++k) s = fminf(s, sbuf[(size_t)k * strideA + i]);
        sa = sqrtf(fmaxf(s, 0.f));
    }
    if (i < m) {
        float s = FLT_MAX;
#pragma unroll
        for (int k = 0; k < S_SLICES; ++k) s = fminf(s, sbB[(size_t)k * strideB + i]);
        const float v = sqrtf(fmaxf(s, 0.f));
        out[1 + i] = v;                  // mins_seeds
        sb_ = v;
    }

#pragma unroll
    for (int off = 32; off > 0; off >>= 1) {
        sa  += __shfl_down(sa,  off, 64);
        sb_ += __shfl_down(sb_, off, 64);
    }
    __shared__ float reda[4], redb[4];
    const int wave = threadIdx.x >> 6;
    const int lane = threadIdx.x & 63;
    if (lane == 0) { reda[wave] = sa; redb[wave] = sb_; }
    __syncthreads();

    if (threadIdx.x == 0) {
        const float ta = reda[0] + reda[1] + reda[2] + reda[3];
        const float tb = redb[0] + redb[1] + redb[2] + redb[3];
        atomicAdd(&hdr[0], ta);
        atomicAdd(&hdr[1], tb);
        __threadfence();
        const unsigned ticket = atomicAdd((unsigned*)&hdr[2], 1u);
        if (ticket == (unsigned)(gridDim.x - 1)) {
            const float fa = atomicAdd(&hdr[0], 0.f);
            const float fb = atomicAdd(&hdr[1], 0.f);
            const float loss = fa / (float)n;
            const float loss_seeds = fb / (float)m;
            out[0] = loss + loss_seeds;
            out[1 + m] = loss;
            out[2 + m] = loss_seeds;
        }
    }
}

extern "C" void kernel_launch(void* const* d_in, const int* in_sizes, int n_in,
                              void* d_out, int out_size, void* d_ws, size_t ws_size,
                              hipStream_t stream) {
    const int n = in_sizes[0] / 3;   // true_pos count
    const int m = in_sizes[1] / 3;   // pred_pos count
    const float* A = (const float*)d_in[0];
    const float* B = (const float*)d_in[1];
    float* out = (float*)d_out;

    const int RTn = (n + 31) / 32, RTm = (m + 31) / 32;
    char* p = (char*)d_ws;
    float*   hdr  = (float*)p;    p += 64;
    float*   sbuf = (float*)p;    p += (size_t)S_SLICES * (RTn + RTm) * 32 * 4;
    ushort8* RFA  = (ushort8*)p;  p += (size_t)RTn * 64 * 16;
    ushort8* CFA  = (ushort8*)p;  p += (size_t)RTn * 64 * 16;
    ushort8* RFB  = (ushort8*)p;  p += (size_t)RTm * 64 * 16;
    ushort8* CFB  = (ushort8*)p;

    const int maxPts = ((RTn > RTm) ? RTn : RTm) * 32;
    prep_kernel<<<(maxPts + 255) / 256, 256, 0, stream>>>(
        A, B, RFA, CFA, RFB, CFB, hdr, n, m, RTn, RTm);

    const int maxRT = (RTn > RTm) ? RTn : RTm;
    dim3 grid((maxRT + 3) / 4, S_SLICES, 2);
    pairmin_kernel<<<grid, 256, 0, stream>>>(
        (const bf16x8*)RFA, (const bf16x8*)CFA,
        (const bf16x8*)RFB, (const bf16x8*)CFB, sbuf, RTn, RTm);

    const int maxnm = (n > m) ? n : m;
    finalize_kernel<<<(maxnm + 255) / 256, 256, 0, stream>>>(
        sbuf, hdr, out, n, m, RTn, RTm);
}

// Round 14
// 78.782 us; speedup vs baseline: 1.0385x; 1.0385x over previous
//
#include <hip/hip_runtime.h>
#include <cfloat>

typedef __bf16 bf16x8 __attribute__((ext_vector_type(8)));
typedef unsigned short ushort8 __attribute__((ext_vector_type(8)));
typedef float f32x16 __attribute__((ext_vector_type(16)));

#define S_SLICES 4   // 96 x 4 x 2 = 768 blocks = 3/CU even
#define CHUNK 8      // tiles per LDS buffer (8 KB)

// fp32 -> bf16 bits, round-to-nearest-even
static __device__ __forceinline__ unsigned short f2bf(float x) {
    unsigned u = __float_as_uint(x);
    return (unsigned short)((u + 0x7FFFu + ((u >> 16) & 1u)) >> 16);
}
static __device__ __forceinline__ float bfbits2f(unsigned short h) {
    return __uint_as_float(((unsigned)h) << 16);
}

// Per point, build TWO 16-element K-vectors (verified round 7/8):
//  row vec: [-2hx,-2hy,-2hz, -2hx,-2hy,-2hz, -2lx,-2ly,-2lz, s1,s2,s3, 1,1,1, 0]
//  col vec: [ hx,  hy,  hz,   lx,  ly,  lz,   hx,  hy,  hz,  1,1,1, t1,t2,t3, 0]
//  => sum_k row[k]*col[k] = nrmRow + nrmCol - 2(hh+hl+lh) ~= d2 (err ~1e-4).
// Fragment storage: frag[tile*64 + q*32 + l5], point = tile*32+l5, k = q*8+j.
// Pad points get nrm=1e30 -> never win a min.
__global__ __launch_bounds__(256) void prep_kernel(
    const float* __restrict__ A, const float* __restrict__ B,
    ushort8* __restrict__ RFA, ushort8* __restrict__ CFA,
    ushort8* __restrict__ RFB, ushort8* __restrict__ CFB,
    float* __restrict__ hdr, int n, int m, int RTn, int RTm)
{
    const int i = blockIdx.x * 256 + threadIdx.x;
    if (i < 8) hdr[i] = 0.f;
    const unsigned short one = 0x3F80;

#pragma unroll
    for (int side = 0; side < 2; ++side) {
        const int cntPts = side ? RTm * 32 : RTn * 32;
        if (i >= cntPts) continue;
        const float* P = side ? B : A;
        const int lim = side ? m : n;
        ushort8* RF = side ? RFB : RFA;
        ushort8* CF = side ? CFB : CFA;

        float x = 0.f, y = 0.f, z = 0.f, nrm = 1e30f;
        if (i < lim) { x = P[3*i]; y = P[3*i+1]; z = P[3*i+2];
                       nrm = fmaf(x, x, fmaf(y, y, z * z)); }
        const unsigned short hx = f2bf(x), hy = f2bf(y), hz = f2bf(z);
        const unsigned short lx = f2bf(x - bfbits2f(hx)),
                             ly = f2bf(y - bfbits2f(hy)),
                             lz = f2bf(z - bfbits2f(hz));
        const unsigned short nhx = f2bf(-2.f * bfbits2f(hx)),
                             nhy = f2bf(-2.f * bfbits2f(hy)),
                             nhz = f2bf(-2.f * bfbits2f(hz));
        const unsigned short nlx = f2bf(-2.f * bfbits2f(lx)),
                             nly = f2bf(-2.f * bfbits2f(ly)),
                             nlz = f2bf(-2.f * bfbits2f(lz));
        float r = nrm;
        const unsigned short s1 = f2bf(r); r -= bfbits2f(s1);
        const unsigned short s2 = f2bf(r); r -= bfbits2f(s2);
        const unsigned short s3 = f2bf(r);

        const int t = i >> 5, l5 = i & 31;
        ushort8 rq0 = { nhx, nhy, nhz, nhx, nhy, nhz, nlx, nly };
        ushort8 rq1 = { nlz, s1, s2, s3, one, one, one, 0 };
        RF[t * 64 + l5]      = rq0;
        RF[t * 64 + 32 + l5] = rq1;
        ushort8 cq0 = { hx, hy, hz, lx, ly, lz, hx, hy };
        ushort8 cq1 = { hz, one, one, one, s1, s2, s3, 0 };
        CF[t * 64 + l5]      = cq0;
        CF[t * 64 + 32 + l5] = cq1;
    }
}

#define MFMA(b) __builtin_amdgcn_mfma_f32_32x32x16_bf16(afrag, (b), zc, 0, 0, 0)
#define MINC(C)                                             \
    _Pragma("unroll")                                       \
    for (int r = 0; r < 16; ++r) macc[r] = fminf(macc[r], (C)[r]);

// z=0: rows=A vs cols=B -> sbuf side 0 ("mins"); z=1: transposed ("mins_seeds").
// Rounds 10-13: per-wave global prefetch queues plateau at ~25-30us — each of
// the 4 waves privately streams the SAME 96KB CF slice (4x redundant vmem).
// Fix (canonical §5): async global->LDS DMA double-buffer. Wave w stages
// tiles 2w,2w+1 of an 8-tile chunk via global_load_lds width=16 (dest =
// wave-uniform base + lane*16); all waves ds_read_b128 from LDS. The chunk-c+1
// DMA is issued right after the barrier and drains a full compute-phase later.
__global__ __launch_bounds__(256, 4) void pairmin_kernel(
    const bf16x8* __restrict__ RFA, const bf16x8* __restrict__ CFA,
    const bf16x8* __restrict__ RFB, const bf16x8* __restrict__ CFB,
    float* __restrict__ sbuf, int RTn, int RTm)
{
    const int lane = threadIdx.x & 63;
    const int wave = threadIdx.x >> 6;

    const bf16x8* RF; const bf16x8* CF; float* sb; int rtCount, ctCount, stride;
    if (blockIdx.z == 0) { RF = RFA; CF = CFB; rtCount = RTn; ctCount = RTm;
                           sb = sbuf; stride = RTn * 32; }
    else                 { RF = RFB; CF = CFA; rtCount = RTm; ctCount = RTn;
                           sb = sbuf + (size_t)S_SLICES * RTn * 32;
                           stride = RTm * 32; }

    // clamp instead of early-return: every wave must reach the barriers
    const int rt = min(blockIdx.x * 4 + wave, rtCount - 1);
    sb += (size_t)blockIdx.y * stride;

    const int ctPer = (ctCount + S_SLICES - 1) / S_SLICES;
    const int ctBeg = min((int)blockIdx.y * ctPer, ctCount - 1);
    const int ctEnd = min(ctBeg + ctPer, ctCount);
    const int last  = ctEnd - 1;
    const int chunks = (ctEnd - ctBeg + CHUNK - 1) / CHUNK;

    const bf16x8 afrag = RF[rt * 64 + lane];         // loop-invariant
    const f32x16 zc = {};

    __shared__ ushort8 LB[2][CHUNK][64];             // 2 x 8KB buffers

    // stage chunk `base..base+7` (clamped; dup tiles are min-idempotent) into LB[buf]
#define STAGE(buf_, base_)                                                     \
    {                                                                          \
        _Pragma("unroll")                                                      \
        for (int j = 0; j < 2; ++j) {                                          \
            const int t = wave * 2 + j;                                        \
            const int g = min((base_) + t, last);                              \
            const char* src = (const char*)CF + ((size_t)g * 64 + lane) * 16;  \
            __builtin_amdgcn_global_load_lds(                                  \
                (const __attribute__((address_space(1))) unsigned*)src,        \
                (__attribute__((address_space(3))) unsigned*)&LB[buf_][t][0],  \
                16, 0, 0);                                                     \
        }                                                                      \
    }

    float macc[16];
#pragma unroll
    for (int r = 0; r < 16; ++r) macc[r] = FLT_MAX;

    STAGE(0, ctBeg);
    int buf = 0;
    for (int c = 0; c < chunks; ++c) {
        __syncthreads();   // drains vmcnt: chunk c staged; buf^1 readers done
        if (c + 1 < chunks) STAGE(buf ^ 1, ctBeg + (c + 1) * CHUNK);
        // process 8 tiles from LDS (always full CHUNK; clamped dups benign)
#pragma unroll
        for (int t = 0; t < CHUNK; t += 2) {
            const bf16x8 b0 = *(const bf16x8*)&LB[buf][t][0 + lane];
            const bf16x8 b1 = *(const bf16x8*)&LB[buf][t + 1][0 + lane];
            const f32x16 C0 = MFMA(b0);
            const f32x16 C1 = MFMA(b1);
            MINC(C0);
            MINC(C1);
        }
        buf ^= 1;
    }

    // reduce row mins across the 32 cols held in each 32-lane half
#pragma unroll
    for (int r = 0; r < 16; ++r) {
        float v = macc[r];
        v = fminf(v, __shfl_xor(v, 1, 64));
        v = fminf(v, __shfl_xor(v, 2, 64));
        v = fminf(v, __shfl_xor(v, 4, 64));
        v = fminf(v, __shfl_xor(v, 8, 64));
        v = fminf(v, __shfl_xor(v, 16, 64));
        macc[r] = v;
    }
    if ((lane & 31) == 0) {
        const int q4i = (lane >> 5) * 4;             // C map: row=(r&3)+8*(r>>2)+4*q
        float* dst = sb + rt * 32;
#pragma unroll
        for (int r = 0; r < 16; ++r)
            dst[(r & 3) + 8 * (r >> 2) + q4i] = macc[r];
    }
}

// out layout: [loss+loss_seeds, mins_seeds(m), loss, loss_seeds]
__global__ __launch_bounds__(256) void finalize_kernel(
    const float* __restrict__ sbuf, float* __restrict__ hdr,
    float* __restrict__ out, int n, int m, int RTn, int RTm)
{
    const int i = blockIdx.x * 256 + threadIdx.x;
    const int strideA = RTn * 32, strideB = RTm * 32;
    const float* sbB = sbuf + (size_t)S_SLICES * strideA;

    float sa = 0.f, sb_ = 0.f;
    if (i < n) {
        float s = FLT_MAX;
#pragma unroll
        for (int k = 0; k < S_SLICES; ++k) s = fminf(s, sbuf[(size_t)k * strideA + i]);
        sa = sqrtf(fmaxf(s, 0.f));
    }
    if (i < m) {
        float s = FLT_MAX;
#pragma unroll
        for (int k = 0; k < S_SLICES; ++k) s = fminf(s, sbB[(size_t)k * strideB + i]);
        const float v = sqrtf(fmaxf(s, 0.f));
        out[1 + i] = v;                  // mins_seeds
        sb_ = v;
    }

#pragma unroll
    for (int off = 32; off > 0; off >>= 1) {
        sa  += __shfl_down(sa,  off, 64);
        sb_ += __shfl_down(sb_, off, 64);
    }
    __shared__ float reda[4], redb[4];
    const int wave = threadIdx.x >> 6;
    const int lane = threadIdx.x & 63;
    if (lane == 0) { reda[wave] = sa; redb[wave] = sb_; }
    __syncthreads();

    if (threadIdx.x == 0) {
        const float ta = reda[0] + reda[1] + reda[2] + reda[3];
        const float tb = redb[0] + redb[1] + redb[2] + redb[3];
        atomicAdd(&hdr[0], ta);
        atomicAdd(&hdr[1], tb);
        __threadfence();
        const unsigned ticket = atomicAdd((unsigned*)&hdr[2], 1u);
        if (ticket == (unsigned)(gridDim.x - 1)) {
            const float fa = atomicAdd(&hdr[0], 0.f);
            const float fb = atomicAdd(&hdr[1], 0.f);
            const float loss = fa / (float)n;
            const float loss_seeds = fb / (float)m;
            out[0] = loss + loss_seeds;
            out[1 + m] = loss;
            out[2 + m] = loss_seeds;
        }
    }
}

extern "C" void kernel_launch(void* const* d_in, const int* in_sizes, int n_in,
                              void* d_out, int out_size, void* d_ws, size_t ws_size,
                              hipStream_t stream) {
    const int n = in_sizes[0] / 3;   // true_pos count
    const int m = in_sizes[1] / 3;   // pred_pos count
    const float* A = (const float*)d_in[0];
    const float* B = (const float*)d_in[1];
    float* out = (float*)d_out;

    const int RTn = (n + 31) / 32, RTm = (m + 31) / 32;
    char* p = (char*)d_ws;
    float*   hdr  = (float*)p;    p += 64;
    float*   sbuf = (float*)p;    p += (size_t)S_SLICES * (RTn + RTm) * 32 * 4;
    ushort8* RFA  = (ushort8*)p;  p += (size_t)RTn * 64 * 16;
    ushort8* CFA  = (ushort8*)p;  p += (size_t)RTn * 64 * 16;
    ushort8* RFB  = (ushort8*)p;  p += (size_t)RTm * 64 * 16;
    ushort8* CFB  = (ushort8*)p;

    const int maxPts = ((RTn > RTm) ? RTn : RTm) * 32;
    prep_kernel<<<(maxPts + 255) / 256, 256, 0, stream>>>(
        A, B, RFA, CFA, RFB, CFB, hdr, n, m, RTn, RTm);

    const int maxRT = (RTn > RTm) ? RTn : RTm;
    dim3 grid((maxRT + 3) / 4, S_SLICES, 2);
    pairmin_kernel<<<grid, 256, 0, stream>>>(
        (const bf16x8*)RFA, (const bf16x8*)CFA,
        (const bf16x8*)RFB, (const bf16x8*)CFB, sbuf, RTn, RTm);

    const int maxnm = (n > m) ? n : m;
    finalize_kernel<<<(maxnm + 255) / 256, 256, 0, stream>>>(
        sbuf, hdr, out, n, m, RTn, RTm);
}

// Round 15
// 77.709 us; speedup vs baseline: 1.0528x; 1.0138x over previous
//
#include <hip/hip_runtime.h>
#include <cfloat>

typedef __bf16 bf16x8 __attribute__((ext_vector_type(8)));
typedef unsigned short ushort8 __attribute__((ext_vector_type(8)));
typedef float f32x16 __attribute__((ext_vector_type(16)));

#define S_SLICES 4   // 96 x 4 x 2 = 768 blocks = 3/CU, fully resident (best measured)

// fp32 -> bf16 bits, round-to-nearest-even
static __device__ __forceinline__ unsigned short f2bf(float x) {
    unsigned u = __float_as_uint(x);
    return (unsigned short)((u + 0x7FFFu + ((u >> 16) & 1u)) >> 16);
}
static __device__ __forceinline__ float bfbits2f(unsigned short h) {
    return __uint_as_float(((unsigned)h) << 16);
}

// Per point, build TWO 16-element K-vectors (verified round 7/8):
//  row vec: [-2hx,-2hy,-2hz, -2hx,-2hy,-2hz, -2lx,-2ly,-2lz, s1,s2,s3, 1,1,1, 0]
//  col vec: [ hx,  hy,  hz,   lx,  ly,  lz,   hx,  hy,  hz,  1,1,1, t1,t2,t3, 0]
//  => sum_k row[k]*col[k] = nrmRow + nrmCol - 2(hh+hl+lh) ~= d2 (err ~1e-4).
// Fragment storage: frag[tile*64 + q*32 + l5], point = tile*32+l5, k = q*8+j.
// Pad points get nrm=1e30 -> never win a min.
__global__ __launch_bounds__(256) void prep_kernel(
    const float* __restrict__ A, const float* __restrict__ B,
    ushort8* __restrict__ RFA, ushort8* __restrict__ CFA,
    ushort8* __restrict__ RFB, ushort8* __restrict__ CFB,
    float* __restrict__ hdr, int n, int m, int RTn, int RTm)
{
    const int i = blockIdx.x * 256 + threadIdx.x;
    if (i < 8) hdr[i] = 0.f;
    const unsigned short one = 0x3F80;

#pragma unroll
    for (int side = 0; side < 2; ++side) {
        const int cntPts = side ? RTm * 32 : RTn * 32;
        if (i >= cntPts) continue;
        const float* P = side ? B : A;
        const int lim = side ? m : n;
        ushort8* RF = side ? RFB : RFA;
        ushort8* CF = side ? CFB : CFA;

        float x = 0.f, y = 0.f, z = 0.f, nrm = 1e30f;
        if (i < lim) { x = P[3*i]; y = P[3*i+1]; z = P[3*i+2];
                       nrm = fmaf(x, x, fmaf(y, y, z * z)); }
        const unsigned short hx = f2bf(x), hy = f2bf(y), hz = f2bf(z);
        const unsigned short lx = f2bf(x - bfbits2f(hx)),
                             ly = f2bf(y - bfbits2f(hy)),
                             lz = f2bf(z - bfbits2f(hz));
        const unsigned short nhx = f2bf(-2.f * bfbits2f(hx)),
                             nhy = f2bf(-2.f * bfbits2f(hy)),
                             nhz = f2bf(-2.f * bfbits2f(hz));
        const unsigned short nlx = f2bf(-2.f * bfbits2f(lx)),
                             nly = f2bf(-2.f * bfbits2f(ly)),
                             nlz = f2bf(-2.f * bfbits2f(lz));
        float r = nrm;
        const unsigned short s1 = f2bf(r); r -= bfbits2f(s1);
        const unsigned short s2 = f2bf(r); r -= bfbits2f(s2);
        const unsigned short s3 = f2bf(r);

        const int t = i >> 5, l5 = i & 31;
        ushort8 rq0 = { nhx, nhy, nhz, nhx, nhy, nhz, nlx, nly };
        ushort8 rq1 = { nlz, s1, s2, s3, one, one, one, 0 };
        RF[t * 64 + l5]      = rq0;
        RF[t * 64 + 32 + l5] = rq1;
        ushort8 cq0 = { hx, hy, hz, lx, ly, lz, hx, hy };
        ushort8 cq1 = { hz, one, one, one, s1, s2, s3, 0 };
        CF[t * 64 + l5]      = cq0;
        CF[t * 64 + 32 + l5] = cq1;
    }
}

#define MFMA(b) __builtin_amdgcn_mfma_f32_32x32x16_bf16(afrag, (b), zc, 0, 0, 0)
#define MINC(C)                                             \
    _Pragma("unroll")                                       \
    for (int r = 0; r < 16; ++r) macc[r] = fminf(macc[r], (C)[r]);
// fuse two C tiles per pass: 16 v_min3_f32 replaces 32 v_fmin_f32
#define MINC3(C0_, C1_)                                     \
    _Pragma("unroll")                                       \
    for (int r = 0; r < 16; ++r)                            \
        macc[r] = fminf(fminf(macc[r], (C0_)[r]), (C1_)[r]);

// z=0: rows=A vs cols=B -> sbuf side 0 ("mins"); z=1: transposed ("mins_seeds").
// R8: (256,4) keeps C in VGPRs. R11: 4-deep queue best (77.2us). R12-R14:
// deeper queues / 2-row tiles / LDS-DMA all neutral-or-worse => limiter is
// VALU issue count, dominated by the per-tile 16 fmins. This round: min3
// fusion halves min instructions (16 min3 per TWO tiles).
__global__ __launch_bounds__(256, 4) void pairmin_kernel(
    const bf16x8* __restrict__ RFA, const bf16x8* __restrict__ CFA,
    const bf16x8* __restrict__ RFB, const bf16x8* __restrict__ CFB,
    float* __restrict__ sbuf, int RTn, int RTm)
{
    const int lane = threadIdx.x & 63;
    const int wave = threadIdx.x >> 6;

    const bf16x8* RF; const bf16x8* CF; float* sb; int rtCount, ctCount, stride;
    if (blockIdx.z == 0) { RF = RFA; CF = CFB; rtCount = RTn; ctCount = RTm;
                           sb = sbuf; stride = RTn * 32; }
    else                 { RF = RFB; CF = CFA; rtCount = RTm; ctCount = RTn;
                           sb = sbuf + (size_t)S_SLICES * RTn * 32;
                           stride = RTm * 32; }

    const int rt = blockIdx.x * 4 + wave;
    if (rt >= rtCount) return;                       // wave-uniform
    sb += (size_t)blockIdx.y * stride;

    const int ctPer = (ctCount + S_SLICES - 1) / S_SLICES;
    const int ctBeg = min(blockIdx.y * ctPer, ctCount);
    const int ctEnd = min(ctBeg + ctPer, ctCount);

    const bf16x8 afrag = RF[rt * 64 + lane];         // loop-invariant
    const f32x16 zc = {};

    float macc[16];
#pragma unroll
    for (int r = 0; r < 16; ++r) macc[r] = FLT_MAX;

    if (ctBeg < ctEnd) {
        int ct = ctBeg;
        const int last = ctEnd - 1;
        // 4-deep prefetch queue (prologue clamped; duplicates min-idempotent)
        bf16x8 q0 = CF[(size_t)ct * 64 + lane];
        bf16x8 q1 = CF[(size_t)min(ct + 1, last) * 64 + lane];
        bf16x8 q2 = CF[(size_t)min(ct + 2, last) * 64 + lane];
        bf16x8 q3 = CF[(size_t)min(ct + 3, last) * 64 + lane];

        // steady state: 4 tiles/iter. Invariant at top: q0..q3 = ct..ct+3.
        for (; ct + 7 < ctEnd; ct += 4) {
            const f32x16 C0 = MFMA(q0);
            const f32x16 C1 = MFMA(q1);
            q0 = CF[(size_t)(ct + 4) * 64 + lane];
            q1 = CF[(size_t)(ct + 5) * 64 + lane];
            MINC3(C0, C1);
            const f32x16 C2 = MFMA(q2);
            const f32x16 C3 = MFMA(q3);
            q2 = CF[(size_t)(ct + 6) * 64 + lane];
            q3 = CF[(size_t)(ct + 7) * 64 + lane];
            MINC3(C2, C3);
        }
        // epilogue: q0..q3 hold tiles ct..ct+3 (clamped dups benign);
        // remaining tiles: ct .. ctEnd-1 (1..7 of them)
        {
            const f32x16 C = MFMA(q0);
            MINC(C);
        }
        if (ct + 1 < ctEnd) { const f32x16 C = MFMA(q1); MINC(C); }
        if (ct + 2 < ctEnd) { const f32x16 C = MFMA(q2); MINC(C); }
        if (ct + 3 < ctEnd) { const f32x16 C = MFMA(q3); MINC(C); }
        for (int t = ct + 4; t < ctEnd; ++t) {
            const bf16x8 b = CF[(size_t)t * 64 + lane];
            const f32x16 C = MFMA(b);
            MINC(C);
        }
    }

    // reduce row mins across the 32 cols held in each 32-lane half
#pragma unroll
    for (int r = 0; r < 16; ++r) {
        float v = macc[r];
        v = fminf(v, __shfl_xor(v, 1, 64));
        v = fminf(v, __shfl_xor(v, 2, 64));
        v = fminf(v, __shfl_xor(v, 4, 64));
        v = fminf(v, __shfl_xor(v, 8, 64));
        v = fminf(v, __shfl_xor(v, 16, 64));
        macc[r] = v;
    }
    if ((lane & 31) == 0) {
        const int q4i = (lane >> 5) * 4;             // C map: row=(r&3)+8*(r>>2)+4*q
        float* dst = sb + rt * 32;
#pragma unroll
        for (int r = 0; r < 16; ++r)
            dst[(r & 3) + 8 * (r >> 2) + q4i] = macc[r];
    }
}

// out layout: [loss+loss_seeds, mins_seeds(m), loss, loss_seeds]
__global__ __launch_bounds__(256) void finalize_kernel(
    const float* __restrict__ sbuf, float* __restrict__ hdr,
    float* __restrict__ out, int n, int m, int RTn, int RTm)
{
    const int i = blockIdx.x * 256 + threadIdx.x;
    const int strideA = RTn * 32, strideB = RTm * 32;
    const float* sbB = sbuf + (size_t)S_SLICES * strideA;

    float sa = 0.f, sb_ = 0.f;
    if (i < n) {
        const float s = fminf(fminf(sbuf[i], sbuf[(size_t)strideA + i]),
                              fminf(sbuf[(size_t)2 * strideA + i],
                                    sbuf[(size_t)3 * strideA + i]));
        sa = sqrtf(fmaxf(s, 0.f));
    }
    if (i < m) {
        const float s = fminf(fminf(sbB[i], sbB[(size_t)strideB + i]),
                              fminf(sbB[(size_t)2 * strideB + i],
                                    sbB[(size_t)3 * strideB + i]));
        const float v = sqrtf(fmaxf(s, 0.f));
        out[1 + i] = v;                  // mins_seeds
        sb_ = v;
    }

#pragma unroll
    for (int off = 32; off > 0; off >>= 1) {
        sa  += __shfl_down(sa,  off, 64);
        sb_ += __shfl_down(sb_, off, 64);
    }
    __shared__ float reda[4], redb[4];
    const int wave = threadIdx.x >> 6;
    const int lane = threadIdx.x & 63;
    if (lane == 0) { reda[wave] = sa; redb[wave] = sb_; }
    __syncthreads();

    if (threadIdx.x == 0) {
        const float ta = reda[0] + reda[1] + reda[2] + reda[3];
        const float tb = redb[0] + redb[1] + redb[2] + redb[3];
        atomicAdd(&hdr[0], ta);
        atomicAdd(&hdr[1], tb);
        __threadfence();
        const unsigned ticket = atomicAdd((unsigned*)&hdr[2], 1u);
        if (ticket == (unsigned)(gridDim.x - 1)) {
            const float fa = atomicAdd(&hdr[0], 0.f);
            const float fb = atomicAdd(&hdr[1], 0.f);
            const float loss = fa / (float)n;
            const float loss_seeds = fb / (float)m;
            out[0] = loss + loss_seeds;
            out[1 + m] = loss;
            out[2 + m] = loss_seeds;
        }
    }
}

extern "C" void kernel_launch(void* const* d_in, const int* in_sizes, int n_in,
                              void* d_out, int out_size, void* d_ws, size_t ws_size,
                              hipStream_t stream) {
    const int n = in_sizes[0] / 3;   // true_pos count
    const int m = in_sizes[1] / 3;   // pred_pos count
    const float* A = (const float*)d_in[0];
    const float* B = (const float*)d_in[1];
    float* out = (float*)d_out;

    const int RTn = (n + 31) / 32, RTm = (m + 31) / 32;
    char* p = (char*)d_ws;
    float*   hdr  = (float*)p;    p += 64;
    float*   sbuf = (float*)p;    p += (size_t)S_SLICES * (RTn + RTm) * 32 * 4;
    ushort8* RFA  = (ushort8*)p;  p += (size_t)RTn * 64 * 16;
    ushort8* CFA  = (ushort8*)p;  p += (size_t)RTn * 64 * 16;
    ushort8* RFB  = (ushort8*)p;  p += (size_t)RTm * 64 * 16;
    ushort8* CFB  = (ushort8*)p;

    const int maxPts = ((RTn > RTm) ? RTn : RTm) * 32;
    prep_kernel<<<(maxPts + 255) / 256, 256, 0, stream>>>(
        A, B, RFA, CFA, RFB, CFB, hdr, n, m, RTn, RTm);

    const int maxRT = (RTn > RTm) ? RTn : RTm;
    dim3 grid((maxRT + 3) / 4, S_SLICES, 2);
    pairmin_kernel<<<grid, 256, 0, stream>>>(
        (const bf16x8*)RFA, (const bf16x8*)CFA,
        (const bf16x8*)RFB, (const bf16x8*)CFB, sbuf, RTn, RTm);

    const int maxnm = (n > m) ? n : m;
    finalize_kernel<<<(maxnm + 255) / 256, 256, 0, stream>>>(
        sbuf, hdr, out, n, m, RTn, RTm);
}